// Round 22
// baseline (862.966 us; speedup 1.0000x reference)
//
#include <hip/hip_runtime.h>
#include <hip/hip_bf16.h>
#include <cstdint>

// ---------------------------------------------------------------------------
// KAN 2-layer forward as two bf16 MFMA GEMMs (fp32 output).
// Round-22 = r18/r21 structure (best, 789us) with the GEMM core switched to
// v_mfma_f32_32x32x16_bf16 (last untested HW lever):
//  * Same FLOP in HALF the MFMA instructions (8 vs 16 per wave per BK=32),
//    same 8 ds_read_b128, same 64 acc regs. ubench: 32x32 = 2382 TF vs
//    16x16 = 2075 (m06/m119). Targets the 57% idle (issue/dep-bound; no
//    pipe saturated: MFMA 43%, HBM 29%, LDS-conflicts 0).
//  * Operand layouts: A/B lane l -> row/col = l&31, k = 8*(l>>5)+e (scaled
//    analog of the r3-verified 16x16 layout); C/D col=l&31,
//    row=(r&3)+8*(r>>2)+4*(l>>5) (HW-verified m74/m101).
//  * Swizzle re-derived for 32-row reads: 8-lane groups hit 16 distinct
//    banks per half -> still 0-conflict with the existing ((row>>1)&3)<<4.
//  * Staging/schedule/vmcnt/XCD-swizzle/aux/ws: r18-VERBATIM.
// ws = r3-proven 255,852,544 B: h1 | W | Aug region. CH=4096.
// ---------------------------------------------------------------------------

typedef __attribute__((ext_vector_type(8))) short short8;
typedef __attribute__((ext_vector_type(4))) short short4v;
typedef __attribute__((ext_vector_type(16))) float f32x16;

#define GLD16(gp, lp)                                                          \
  __builtin_amdgcn_global_load_lds(                                           \
      (const __attribute__((address_space(1))) unsigned int*)(gp),             \
      (__attribute__((address_space(3))) unsigned int*)(lp), 16, 0, 0)

__device__ __forceinline__ unsigned short f2bf(float f) {
  __hip_bfloat16 h = __float2bfloat16(f);
  return *reinterpret_cast<unsigned short*>(&h);
}

__device__ __forceinline__ void basis8(float x, float* w, int& j) {
  float u  = (x + 2.2f) * 2.5f;
  float fj = floorf(u);
  j = (int)fj;
  float t  = u - fj;
  float omt = 1.0f - t;
  float t2 = t * t, t3 = t2 * t;
  w[0] = omt * omt * omt * (1.0f / 6.0f);                              // d==3
  w[1] = (3.0f * t3 - 6.0f * t2 + 4.0f) * (1.0f / 6.0f);               // d==2
  w[2] = (-3.0f * t3 + 3.0f * t2 + 3.0f * t + 1.0f) * (1.0f / 6.0f);   // d==1
  w[3] = t3 * (1.0f / 6.0f);                                           // d==0
}

// ---- prep_w item: W[o, kperm(c,i)], kperm = (i/64)*576 + c*64 + (i%64) ----
__device__ __forceinline__ void prep_w_item(
    long idx, const float* __restrict__ coef, const float* __restrict__ sb,
    const float* __restrict__ sp, const float* __restrict__ mask,
    __hip_bfloat16* __restrict__ W, int I) {
  int qtr = I >> 2;
  int iq = (int)(idx % qtr);
  int o  = (int)(idx / qtr);
  int i  = iq << 2;
  size_t oi = (size_t)o * I + i;
  float4 mk4 = *(const float4*)(mask + oi);
  float4 sp4 = *(const float4*)(sp + oi);
  float4 sb4 = *(const float4*)(sb + oi);
  float spm[4] = {sp4.x * mk4.x, sp4.y * mk4.y, sp4.z * mk4.z, sp4.w * mk4.w};
  float cf[4][8];
  const float4* cp = (const float4*)(coef + oi * 8);
#pragma unroll
  for (int e = 0; e < 4; e++) {
    float4 a = cp[e * 2], b = cp[e * 2 + 1];
    cf[e][0] = a.x; cf[e][1] = a.y; cf[e][2] = a.z; cf[e][3] = a.w;
    cf[e][4] = b.x; cf[e][5] = b.y; cf[e][6] = b.z; cf[e][7] = b.w;
  }
  __hip_bfloat16* base = W + (size_t)o * (size_t)(9 * I) + (i >> 6) * 576 + (i & 63);
#pragma unroll
  for (int c = 0; c < 8; c++) {
    short4v pk;
#pragma unroll
    for (int e = 0; e < 4; e++) pk[e] = (short)f2bf(cf[e][c] * spm[e]);
    *(short4v*)(base + c * 64) = pk;
  }
  short4v ps;
  ps[0] = (short)f2bf(sb4.x * mk4.x); ps[1] = (short)f2bf(sb4.y * mk4.y);
  ps[2] = (short)f2bf(sb4.z * mk4.z); ps[3] = (short)f2bf(sb4.w * mk4.w);
  *(short4v*)(base + 8 * 64) = ps;
}

// ---- expand item: Aug[b, kperm(c,i)], 8 elems ------------------------------
__device__ __forceinline__ void expand_item(
    long idx, const float* __restrict__ src, __hip_bfloat16* __restrict__ aug,
    int I) {
  int  oct = I >> 3;
  int  io = (int)(idx % oct);
  long b  = idx / oct;
  int  i  = io << 3;
  const float* sp = src + b * (size_t)I + i;
  float4 xa = *(const float4*)sp;
  float4 xb = *(const float4*)(sp + 4);
  float xv[8] = {xa.x, xa.y, xa.z, xa.w, xb.x, xb.y, xb.z, xb.w};

  float w[8][4], s[8];
  int   j[8];
#pragma unroll
  for (int e = 0; e < 8; e++) {
    float xe = xv[e];
    s[e] = xe / (1.0f + __expf(-xe));
    basis8(xe, w[e], j[e]);
  }
  __hip_bfloat16* base = aug + b * (size_t)(9 * I) + (i >> 6) * 576 + (i & 63);
#pragma unroll
  for (int c = 0; c < 8; c++) {
    short8 pk;
#pragma unroll
    for (int e = 0; e < 8; e++) {
      int d = j[e] - c;
      float v = 0.0f;
      v = (d == 0) ? w[e][3] : v;
      v = (d == 1) ? w[e][2] : v;
      v = (d == 2) ? w[e][1] : v;
      v = (d == 3) ? w[e][0] : v;
      pk[e] = (short)f2bf(v);
    }
    *(short8*)(base + c * 64) = pk;
  }
  short8 ps;
#pragma unroll
  for (int e = 0; e < 8; e++) ps[e] = (short)f2bf(s[e]);
  *(short8*)(base + 8 * 64) = ps;
}

// ---- merged prep: {W-pack items} then {expand octets} ----------------------
__global__ void prep_merge(
    const float* __restrict__ coef, const float* __restrict__ sb,
    const float* __restrict__ sp, const float* __restrict__ mask,
    __hip_bfloat16* __restrict__ W, int IW, long nW,
    const float* __restrict__ xsrc, __hip_bfloat16* __restrict__ aug,
    int IX, long nX) {
  long idx = (long)blockIdx.x * blockDim.x + threadIdx.x;
  if (idx < nW)            prep_w_item(idx, coef, sb, sp, mask, W, IW);
  else if (idx < nW + nX)  expand_item(idx - nW, xsrc, aug, IX);
}

__global__ void expand_aug(const float* __restrict__ src,
                           __hip_bfloat16* __restrict__ aug,
                           long totalOcts, int I) {
  long idx = (long)blockIdx.x * blockDim.x + threadIdx.x;
  if (idx >= totalOcts) return;
  expand_item(idx, src, aug, I);
}

// ---- 128xBN GEMM, 32x32x16 core: C = A*Bw^T + bias, fp32 out ---------------
// BM=128, BN 256/128, BK=32, 8 waves 2Mx4N (per-wave 64 x BN/4), 3 buffers,
// depth-2 counted vmcnt, 0-conflict swizzle both-sides, XCD swizzle, setprio.
// Per wave per tile: 2x(NF)x2 mfma_32x32x16 (8/4 instr) from 4+2*NF b128 reads.
template <int BN>
__global__ __launch_bounds__(512, 4) void gemm128(
    const __hip_bfloat16* __restrict__ A, const __hip_bfloat16* __restrict__ Bw,
    const float* __restrict__ bias, float* __restrict__ Cout, int N, int K) {
  constexpr int WN   = BN / 4;        // per-wave cols (64 / 32)
  constexpr int NF   = WN / 32;       // 32-col frags per wave (2 / 1)
  constexpr int BUFB = 8192 + BN * 64;
  __shared__ __attribute__((aligned(16))) char lds[3 * BUFB];

  const int t = threadIdx.x;
  const int w = t >> 6, l = t & 63;
  const int wr = w >> 2, wc = w & 3;
  const int lr32 = l & 31, hi = l >> 5;

  unsigned nwg = gridDim.x * gridDim.y;
  unsigned lin = blockIdx.y * gridDim.x + blockIdx.x;
  unsigned swz = (lin & 7) * (nwg >> 3) + (lin >> 3);
  unsigned bx = swz % gridDim.x, by = swz / gridDim.x;
  size_t brow = (size_t)by * 128, bcol = (size_t)bx * BN;

  f32x16 acc[2][NF];
#pragma unroll
  for (int m = 0; m < 2; m++)
#pragma unroll
    for (int n = 0; n < NF; n++)
#pragma unroll
      for (int r = 0; r < 16; r++) acc[m][n][r] = 0.f;

  const int srow  = t >> 2;
  const int scolb = ((t & 3) * 16) ^ (((srow >> 1) & 3) << 4);
  const __hip_bfloat16* gA0 = A + (brow + srow) * (size_t)K + (scolb >> 1);
  const __hip_bfloat16* gB0 = Bw + (bcol + srow) * (size_t)K + (scolb >> 1);
  const __hip_bfloat16* gB1 = gB0 + (size_t)128 * K;

  char* ldsp = (char*)lds;
  // fragment read offsets: frag (row0, ks) -> lane byte =
  //   row*64 + ((ks*32 + hi*16) ^ (((row>>1)&3)<<4)), row = row0 + lr32
  int aoff[2][2], boff[NF][2];
#pragma unroll
  for (int m = 0; m < 2; m++) {
    int row = wr * 64 + m * 32 + lr32;
    int sz = ((row >> 1) & 3) << 4;
#pragma unroll
    for (int ks = 0; ks < 2; ks++)
      aoff[m][ks] = row * 64 + ((ks * 32 + hi * 16) ^ sz);
  }
#pragma unroll
  for (int n = 0; n < NF; n++) {
    int row = wc * WN + n * 32 + lr32;
    int sz = ((row >> 1) & 3) << 4;
#pragma unroll
    for (int ks = 0; ks < 2; ks++)
      boff[n][ks] = 8192 + row * 64 + ((ks * 32 + hi * 16) ^ sz);
  }

  auto STAGE = [&](int kt, int q) {
    char* bp = ldsp + q * BUFB;
    GLD16(gA0 + (kt << 5), bp + w * 1024);
    GLD16(gB0 + (kt << 5), bp + 8192 + w * 1024);
    if constexpr (BN == 256) GLD16(gB1 + (kt << 5), bp + 16384 + w * 1024);
  };
  auto COMPUTE = [&](int q) {
    const char* bb = ldsp + q * BUFB;
    short8 aq[2][2], bq[NF][2];
#pragma unroll
    for (int n = 0; n < NF; n++)
#pragma unroll
      for (int ks = 0; ks < 2; ks++) bq[n][ks] = *(const short8*)(bb + boff[n][ks]);
#pragma unroll
    for (int m = 0; m < 2; m++)
#pragma unroll
      for (int ks = 0; ks < 2; ks++) aq[m][ks] = *(const short8*)(bb + aoff[m][ks]);
    __builtin_amdgcn_s_setprio(1);
#pragma unroll
    for (int m = 0; m < 2; m++)
#pragma unroll
      for (int n = 0; n < NF; n++)
#pragma unroll
        for (int ks = 0; ks < 2; ks++)
          acc[m][n] = __builtin_amdgcn_mfma_f32_32x32x16_bf16(
              aq[m][ks], bq[n][ks], acc[m][n], 0, 0, 0);
    __builtin_amdgcn_s_setprio(0);
    __builtin_amdgcn_s_barrier();   // all waves' reads of buf q retired
  };
  auto VM0 = [&]() { asm volatile("s_waitcnt vmcnt(0)" ::: "memory"); };
  auto VML = [&]() {
    if constexpr (BN == 256) asm volatile("s_waitcnt vmcnt(3)" ::: "memory");
    else                     asm volatile("s_waitcnt vmcnt(2)" ::: "memory");
  };
  auto VM2L = [&]() {
    if constexpr (BN == 256) asm volatile("s_waitcnt vmcnt(6)" ::: "memory");
    else                     asm volatile("s_waitcnt vmcnt(4)" ::: "memory");
  };

  const int NT = K >> 5;   // 288 (L0) / 576 (L1)

  STAGE(0, 0);
  STAGE(1, 1);
  VML();
  __builtin_amdgcn_s_barrier();

  int q0 = 0;
  for (int kt = 0; kt < NT - 2; ++kt) {
    int q2 = q0 + 2; if (q2 >= 3) q2 -= 3;
    STAGE(kt + 2, q2);
    VM2L();
    __builtin_amdgcn_s_barrier();
    COMPUTE(q0);
    q0 = (q0 == 2) ? 0 : q0 + 1;
  }
  VML();
  __builtin_amdgcn_s_barrier();
  COMPUTE(q0);
  q0 = (q0 == 2) ? 0 : q0 + 1;
  VM0();
  __builtin_amdgcn_s_barrier();
  COMPUTE(q0);

  // epilogue: C/D layout col = l&31, row = (r&3) + 8*(r>>2) + 4*hi
#pragma unroll
  for (int n = 0; n < NF; n++) {
    size_t col = bcol + (size_t)wc * WN + n * 32 + lr32;
    float bv = bias[col];
#pragma unroll
    for (int m = 0; m < 2; m++) {
      size_t rbase = brow + (size_t)wr * 64 + m * 32 + 4 * hi;
#pragma unroll
      for (int r = 0; r < 16; r++) {
        size_t row = rbase + (r & 3) + 8 * (r >> 2);
        __builtin_nontemporal_store(acc[m][n][r] + bv,
                                    &Cout[row * (size_t)N + col]);
      }
    }
  }
}

// ---------------------------------------------------------------------------
extern "C" void kernel_launch(void* const* d_in, const int* in_sizes, int n_in,
                              void* d_out, int out_size, void* d_ws, size_t ws_size,
                              hipStream_t stream) {
  const float* x     = (const float*)d_in[0];
  const float* coef0 = (const float*)d_in[1];
  const float* sb0   = (const float*)d_in[2];
  const float* sp0   = (const float*)d_in[3];
  const float* mask0 = (const float*)d_in[4];
  const float* bias0 = (const float*)d_in[5];
  const float* coef1 = (const float*)d_in[6];
  const float* sb1   = (const float*)d_in[7];
  const float* sp1   = (const float*)d_in[8];
  const float* mask1 = (const float*)d_in[9];
  const float* bias1 = (const float*)d_in[10];
  float* out = (float*)d_out;

  const int B = 8192, D0 = 1024, D1 = 2048, D2 = 1024;
  const int K0 = 9 * D0;   // 9216
  const int K1 = 9 * D1;   // 18432
  const int CH = 4096;     // L1 batch chunk

  // ws (255,852,544 B total — r3-PROVEN):
  //   h1  [0, 67108864) | W [67108864, 104857600) | Aug [104857600, +151MB)
  char* ws = (char*)d_ws;
  float*          h1  = (float*)ws;
  __hip_bfloat16* W   = (__hip_bfloat16*)(ws + (size_t)67108864);
  __hip_bfloat16* Aug = (__hip_bfloat16*)(ws + (size_t)104857600);

  const long nW0 = (long)D1 * (D0 / 4);   // 524288
  const long nX0 = (long)B * (D0 / 8);    // 1048576
  const long nW1 = (long)D2 * (D1 / 4);   // 524288
  const long nX1 = (long)CH * (D1 / 8);   // 1048576

  // ---- layer 0: merged prep (W0 + Aug0), GEMM at 2 blocks/CU ----
  prep_merge<<<(unsigned)((nW0 + nX0) / 256), 256, 0, stream>>>(
      coef0, sb0, sp0, mask0, W, D0, nW0, x, Aug, D0, nX0);
  {
    dim3 g0(D1 / 256, B / 128);   // (8, 64) = 512 blocks
    gemm128<256><<<g0, 512, 0, stream>>>(Aug, W, bias0, h1, D1, K0);
  }

  // ---- layer 1: merged prep (W1 + Aug1 ch0), GEMM, expand ch1, GEMM ----
  prep_merge<<<(unsigned)((nW1 + nX1) / 256), 256, 0, stream>>>(
      coef1, sb1, sp1, mask1, W, D1, nW1, h1, Aug, D1, nX1);
  {
    dim3 g1(D2 / 128, CH / 128);   // (8, 32) = 256 blocks
    gemm128<128><<<g1, 512, 0, stream>>>(Aug, W, bias1, out, D2, K1);
  }
  expand_aug<<<(unsigned)(nX1 / 256), 256, 0, stream>>>(
      h1 + (size_t)CH * D1, Aug, nX1, D1);
  {
    dim3 g1(D2 / 128, CH / 128);
    gemm128<128><<<g1, 512, 0, stream>>>(Aug, W, bias1,
                                         out + (size_t)CH * D2, D2, K1);
  }
}

// Round 23
// 795.637 us; speedup vs baseline: 1.0846x; 1.0846x over previous
//
#include <hip/hip_runtime.h>
#include <hip/hip_bf16.h>
#include <cstdint>

// ---------------------------------------------------------------------------
// KAN 2-layer forward as two bf16 MFMA GEMMs (fp32 output).
// Round-23 = REVERT to r21 (session best, 789.4us). r22's 32x32-MFMA core
// regressed (863us: the ((row>>1)&3)<<4 swizzle is NOT conflict-free for the
// 32-row fragment pattern -> 3.8e7 bank conflicts; L1 chunks 165->270us).
// Final structure:
//  * gemm128: BM=128 x BN(256 L0 / 128 L1), BK=32, 8 waves 2Mx4N,
//    16x16x32 MFMA, 3 LDS buffers, depth-2 prefetch with counted vmcnt
//    (never 0 mid-loop), 0-conflict XOR swizzle both-sides, XCD-bijective
//    block swizzle, setprio around MFMA, (512,4) = 2 blocks/CU,
//    non-temporal C-stores.
//  * aux: prep_merge {W-pack + expand} merged dispatches, kperm-576 layout
//    (full-128B-line channel stores), 8-elem/thread expand.
//  * ws = r3-proven 255,852,544 B: h1 | W | Aug region; CH=4096 L1 chunks.
// Adjudicated-null/negative: 4 schedule variants, 3+ occupancy pushes,
// split-K, BN=64, fusion (x2), kperm i-block width, nt-stores (null),
// 32x32 MFMA. Best remaining known lever (MX-fp8) is numerically unsafe
// (est. absmax ~2 >> 0.294 threshold).
// ---------------------------------------------------------------------------

typedef __attribute__((ext_vector_type(8))) short short8;
typedef __attribute__((ext_vector_type(4))) short short4v;
typedef __attribute__((ext_vector_type(4))) float f32x4;

#define GLD16(gp, lp)                                                          \
  __builtin_amdgcn_global_load_lds(                                           \
      (const __attribute__((address_space(1))) unsigned int*)(gp),             \
      (__attribute__((address_space(3))) unsigned int*)(lp), 16, 0, 0)

__device__ __forceinline__ unsigned short f2bf(float f) {
  __hip_bfloat16 h = __float2bfloat16(f);
  return *reinterpret_cast<unsigned short*>(&h);
}

__device__ __forceinline__ void basis8(float x, float* w, int& j) {
  float u  = (x + 2.2f) * 2.5f;
  float fj = floorf(u);
  j = (int)fj;
  float t  = u - fj;
  float omt = 1.0f - t;
  float t2 = t * t, t3 = t2 * t;
  w[0] = omt * omt * omt * (1.0f / 6.0f);                              // d==3
  w[1] = (3.0f * t3 - 6.0f * t2 + 4.0f) * (1.0f / 6.0f);               // d==2
  w[2] = (-3.0f * t3 + 3.0f * t2 + 3.0f * t + 1.0f) * (1.0f / 6.0f);   // d==1
  w[3] = t3 * (1.0f / 6.0f);                                           // d==0
}

// ---- prep_w item: W[o, kperm(c,i)], kperm = (i/64)*576 + c*64 + (i%64) ----
__device__ __forceinline__ void prep_w_item(
    long idx, const float* __restrict__ coef, const float* __restrict__ sb,
    const float* __restrict__ sp, const float* __restrict__ mask,
    __hip_bfloat16* __restrict__ W, int I) {
  int qtr = I >> 2;
  int iq = (int)(idx % qtr);
  int o  = (int)(idx / qtr);
  int i  = iq << 2;
  size_t oi = (size_t)o * I + i;
  float4 mk4 = *(const float4*)(mask + oi);
  float4 sp4 = *(const float4*)(sp + oi);
  float4 sb4 = *(const float4*)(sb + oi);
  float spm[4] = {sp4.x * mk4.x, sp4.y * mk4.y, sp4.z * mk4.z, sp4.w * mk4.w};
  float cf[4][8];
  const float4* cp = (const float4*)(coef + oi * 8);
#pragma unroll
  for (int e = 0; e < 4; e++) {
    float4 a = cp[e * 2], b = cp[e * 2 + 1];
    cf[e][0] = a.x; cf[e][1] = a.y; cf[e][2] = a.z; cf[e][3] = a.w;
    cf[e][4] = b.x; cf[e][5] = b.y; cf[e][6] = b.z; cf[e][7] = b.w;
  }
  __hip_bfloat16* base = W + (size_t)o * (size_t)(9 * I) + (i >> 6) * 576 + (i & 63);
#pragma unroll
  for (int c = 0; c < 8; c++) {
    short4v pk;
#pragma unroll
    for (int e = 0; e < 4; e++) pk[e] = (short)f2bf(cf[e][c] * spm[e]);
    *(short4v*)(base + c * 64) = pk;
  }
  short4v ps;
  ps[0] = (short)f2bf(sb4.x * mk4.x); ps[1] = (short)f2bf(sb4.y * mk4.y);
  ps[2] = (short)f2bf(sb4.z * mk4.z); ps[3] = (short)f2bf(sb4.w * mk4.w);
  *(short4v*)(base + 8 * 64) = ps;
}

// ---- expand item: Aug[b, kperm(c,i)], 8 elems ------------------------------
__device__ __forceinline__ void expand_item(
    long idx, const float* __restrict__ src, __hip_bfloat16* __restrict__ aug,
    int I) {
  int  oct = I >> 3;
  int  io = (int)(idx % oct);
  long b  = idx / oct;
  int  i  = io << 3;
  const float* sp = src + b * (size_t)I + i;
  float4 xa = *(const float4*)sp;
  float4 xb = *(const float4*)(sp + 4);
  float xv[8] = {xa.x, xa.y, xa.z, xa.w, xb.x, xb.y, xb.z, xb.w};

  float w[8][4], s[8];
  int   j[8];
#pragma unroll
  for (int e = 0; e < 8; e++) {
    float xe = xv[e];
    s[e] = xe / (1.0f + __expf(-xe));
    basis8(xe, w[e], j[e]);
  }
  __hip_bfloat16* base = aug + b * (size_t)(9 * I) + (i >> 6) * 576 + (i & 63);
#pragma unroll
  for (int c = 0; c < 8; c++) {
    short8 pk;
#pragma unroll
    for (int e = 0; e < 8; e++) {
      int d = j[e] - c;
      float v = 0.0f;
      v = (d == 0) ? w[e][3] : v;
      v = (d == 1) ? w[e][2] : v;
      v = (d == 2) ? w[e][1] : v;
      v = (d == 3) ? w[e][0] : v;
      pk[e] = (short)f2bf(v);
    }
    *(short8*)(base + c * 64) = pk;
  }
  short8 ps;
#pragma unroll
  for (int e = 0; e < 8; e++) ps[e] = (short)f2bf(s[e]);
  *(short8*)(base + 8 * 64) = ps;
}

// ---- merged prep: {W-pack items} then {expand octets} ----------------------
__global__ void prep_merge(
    const float* __restrict__ coef, const float* __restrict__ sb,
    const float* __restrict__ sp, const float* __restrict__ mask,
    __hip_bfloat16* __restrict__ W, int IW, long nW,
    const float* __restrict__ xsrc, __hip_bfloat16* __restrict__ aug,
    int IX, long nX) {
  long idx = (long)blockIdx.x * blockDim.x + threadIdx.x;
  if (idx < nW)            prep_w_item(idx, coef, sb, sp, mask, W, IW);
  else if (idx < nW + nX)  expand_item(idx - nW, xsrc, aug, IX);
}

__global__ void expand_aug(const float* __restrict__ src,
                           __hip_bfloat16* __restrict__ aug,
                           long totalOcts, int I) {
  long idx = (long)blockIdx.x * blockDim.x + threadIdx.x;
  if (idx >= totalOcts) return;
  expand_item(idx, src, aug, I);
}

// ---- 128xBN GEMM (r15/r18 schedule; nt C-store): C = A*Bw^T + bias ---------
// BM=128, BN 256/128, BK=32, 8 waves 2Mx4N, 3 buffers, depth-2 counted vmcnt.
// LDS 72/48KB -> 2 blocks/CU at (512,4). 0-conflict swizzle both-sides.
template <int BN>
__global__ __launch_bounds__(512, 4) void gemm128(
    const __hip_bfloat16* __restrict__ A, const __hip_bfloat16* __restrict__ Bw,
    const float* __restrict__ bias, float* __restrict__ Cout, int N, int K) {
  constexpr int WN   = BN / 4;
  constexpr int NREP = BN / 64;
  constexpr int BUFB = 8192 + BN * 64;
  __shared__ __attribute__((aligned(16))) char lds[3 * BUFB];

  const int t = threadIdx.x;
  const int w = t >> 6, l = t & 63;
  const int wr = w >> 2, wc = w & 3;
  const int lr = l & 15;
  const int kbs = ((l >> 4) * 16) ^ (((lr >> 1) & 3) << 4);

  unsigned nwg = gridDim.x * gridDim.y;
  unsigned lin = blockIdx.y * gridDim.x + blockIdx.x;
  unsigned swz = (lin & 7) * (nwg >> 3) + (lin >> 3);
  unsigned bx = swz % gridDim.x, by = swz / gridDim.x;
  size_t brow = (size_t)by * 128, bcol = (size_t)bx * BN;

  f32x4 acc[4][NREP];
#pragma unroll
  for (int m = 0; m < 4; m++)
#pragma unroll
    for (int n = 0; n < NREP; n++) acc[m][n] = (f32x4){0.f, 0.f, 0.f, 0.f};

  const int srow  = t >> 2;
  const int scolb = ((t & 3) * 16) ^ (((srow >> 1) & 3) << 4);
  const __hip_bfloat16* gA0 = A + (brow + srow) * (size_t)K + (scolb >> 1);
  const __hip_bfloat16* gB0 = Bw + (bcol + srow) * (size_t)K + (scolb >> 1);
  const __hip_bfloat16* gB1 = gB0 + (size_t)128 * K;

  char* ldsp = (char*)lds;
  const int paOff = (wr * 64 + lr) * 64 + kbs;
  const int pbOff = 8192 + (wc * WN + lr) * 64 + kbs;

  auto STAGE = [&](int kt, int q) {
    char* bp = ldsp + q * BUFB;
    GLD16(gA0 + (kt << 5), bp + w * 1024);
    GLD16(gB0 + (kt << 5), bp + 8192 + w * 1024);
    if constexpr (BN == 256) GLD16(gB1 + (kt << 5), bp + 16384 + w * 1024);
  };
  auto COMPUTE = [&](int q) {
    const char* pa = ldsp + q * BUFB + paOff;
    const char* pb = ldsp + q * BUFB + pbOff;
    short8 bq[NREP], aq[4];
#pragma unroll
    for (int n = 0; n < NREP; n++) bq[n] = *(const short8*)(pb + n * 1024);
#pragma unroll
    for (int m = 0; m < 4; m++) aq[m] = *(const short8*)(pa + m * 1024);
    __builtin_amdgcn_s_setprio(1);
#pragma unroll
    for (int m = 0; m < 4; m++)
#pragma unroll
      for (int n = 0; n < NREP; n++)
        acc[m][n] = __builtin_amdgcn_mfma_f32_16x16x32_bf16(aq[m], bq[n], acc[m][n], 0, 0, 0);
    __builtin_amdgcn_s_setprio(0);
    __builtin_amdgcn_s_barrier();
  };
  auto VM0 = [&]() { asm volatile("s_waitcnt vmcnt(0)" ::: "memory"); };
  auto VML = [&]() {
    if constexpr (BN == 256) asm volatile("s_waitcnt vmcnt(3)" ::: "memory");
    else                     asm volatile("s_waitcnt vmcnt(2)" ::: "memory");
  };
  auto VM2L = [&]() {
    if constexpr (BN == 256) asm volatile("s_waitcnt vmcnt(6)" ::: "memory");
    else                     asm volatile("s_waitcnt vmcnt(4)" ::: "memory");
  };

  const int NT = K >> 5;

  STAGE(0, 0);
  STAGE(1, 1);
  VML();
  __builtin_amdgcn_s_barrier();

  int q0 = 0;
  for (int kt = 0; kt < NT - 2; ++kt) {
    int q2 = q0 + 2; if (q2 >= 3) q2 -= 3;
    STAGE(kt + 2, q2);
    VM2L();
    __builtin_amdgcn_s_barrier();
    COMPUTE(q0);
    q0 = (q0 == 2) ? 0 : q0 + 1;
  }
  VML();
  __builtin_amdgcn_s_barrier();
  COMPUTE(q0);
  q0 = (q0 == 2) ? 0 : q0 + 1;
  VM0();
  __builtin_amdgcn_s_barrier();
  COMPUTE(q0);

  // epilogue: non-temporal C-stores (evict-first; C is never re-read soon)
  const int orow = (l >> 4) << 2;
#pragma unroll
  for (int n = 0; n < NREP; n++) {
    size_t col = bcol + (size_t)wc * WN + n * 16 + lr;
    float bv = bias[col];
#pragma unroll
    for (int m = 0; m < 4; m++) {
      size_t row = brow + (size_t)wr * 64 + m * 16 + orow;
#pragma unroll
      for (int r = 0; r < 4; r++)
        __builtin_nontemporal_store(acc[m][n][r] + bv,
                                    &Cout[(row + r) * (size_t)N + col]);
    }
  }
}

// ---------------------------------------------------------------------------
extern "C" void kernel_launch(void* const* d_in, const int* in_sizes, int n_in,
                              void* d_out, int out_size, void* d_ws, size_t ws_size,
                              hipStream_t stream) {
  const float* x     = (const float*)d_in[0];
  const float* coef0 = (const float*)d_in[1];
  const float* sb0   = (const float*)d_in[2];
  const float* sp0   = (const float*)d_in[3];
  const float* mask0 = (const float*)d_in[4];
  const float* bias0 = (const float*)d_in[5];
  const float* coef1 = (const float*)d_in[6];
  const float* sb1   = (const float*)d_in[7];
  const float* sp1   = (const float*)d_in[8];
  const float* mask1 = (const float*)d_in[9];
  const float* bias1 = (const float*)d_in[10];
  float* out = (float*)d_out;

  const int B = 8192, D0 = 1024, D1 = 2048, D2 = 1024;
  const int K0 = 9 * D0;   // 9216
  const int K1 = 9 * D1;   // 18432
  const int CH = 4096;     // L1 batch chunk

  // ws (255,852,544 B total — r3-PROVEN):
  //   h1  [0, 67108864) | W [67108864, 104857600) | Aug [104857600, +151MB)
  char* ws = (char*)d_ws;
  float*          h1  = (float*)ws;
  __hip_bfloat16* W   = (__hip_bfloat16*)(ws + (size_t)67108864);
  __hip_bfloat16* Aug = (__hip_bfloat16*)(ws + (size_t)104857600);

  const long nW0 = (long)D1 * (D0 / 4);   // 524288
  const long nX0 = (long)B * (D0 / 8);    // 1048576
  const long nW1 = (long)D2 * (D1 / 4);   // 524288
  const long nX1 = (long)CH * (D1 / 8);   // 1048576

  // ---- layer 0: merged prep (W0 + Aug0), GEMM at 2 blocks/CU ----
  prep_merge<<<(unsigned)((nW0 + nX0) / 256), 256, 0, stream>>>(
      coef0, sb0, sp0, mask0, W, D0, nW0, x, Aug, D0, nX0);
  {
    dim3 g0(D1 / 256, B / 128);   // (8, 64) = 512 blocks
    gemm128<256><<<g0, 512, 0, stream>>>(Aug, W, bias0, h1, D1, K0);
  }

  // ---- layer 1: merged prep (W1 + Aug1 ch0), GEMM, expand ch1, GEMM ----
  prep_merge<<<(unsigned)((nW1 + nX1) / 256), 256, 0, stream>>>(
      coef1, sb1, sp1, mask1, W, D1, nW1, h1, Aug, D1, nX1);
  {
    dim3 g1(D2 / 128, CH / 128);   // (8, 32) = 256 blocks
    gemm128<128><<<g1, 512, 0, stream>>>(Aug, W, bias1, out, D2, K1);
  }
  expand_aug<<<(unsigned)(nX1 / 256), 256, 0, stream>>>(
      h1 + (size_t)CH * D1, Aug, nX1, D1);
  {
    dim3 g1(D2 / 128, CH / 128);
    gemm128<128><<<g1, 512, 0, stream>>>(Aug, W, bias1,
                                         out + (size_t)CH * D2, D2, K1);
  }
}